// Round 1
// baseline (668.785 us; speedup 1.0000x reference)
//
#include <hip/hip_runtime.h>
#include <hip/hip_bf16.h>

// Problem constants (fixed by reference): D=4, B=2, S=4096, DIN_S=512, DOUT_S=2048
#define D_   4
#define M_   8192      // B*S
#define K_   2048      // D*DIN_S
#define N_   2048      // DOUT_S
#define DIN  512

typedef __attribute__((ext_vector_type(8))) short  short8v;   // 8 bf16 = 4 VGPRs (MFMA A/B frag)
typedef __attribute__((ext_vector_type(4))) float  f32x4;     // MFMA C/D frag

// fp32 -> bf16, round-to-nearest-even
__device__ __forceinline__ unsigned short f2bf(float f) {
  union { float f; unsigned int u; } v; v.f = f;
  unsigned int u = v.u;
  return (unsigned short)((u + 0x7fffu + ((u >> 16) & 1u)) >> 16);
}

// --- Kernel 1: x [i][m][k] fp32 -> A [m][i*512+k] bf16 (row-major M x K) -----
__global__ __launch_bounds__(256) void convert_x_kernel(const float* __restrict__ x,
                                                        unsigned short* __restrict__ A) {
  unsigned int tid = blockIdx.x * 256u + threadIdx.x;   // [0, M_*K_/8)
  unsigned int kg  = tid & 63u;
  unsigned int i   = (tid >> 6) & 3u;
  unsigned int m   = tid >> 8;
  const float4* src = (const float4*)(x + (size_t)i * ((size_t)M_ * DIN)
                                        + (size_t)m * DIN + (size_t)kg * 8);
  float4 a = src[0];
  float4 b = src[1];
  uint4 pk;
  pk.x = (unsigned int)f2bf(a.x) | ((unsigned int)f2bf(a.y) << 16);
  pk.y = (unsigned int)f2bf(a.z) | ((unsigned int)f2bf(a.w) << 16);
  pk.z = (unsigned int)f2bf(b.x) | ((unsigned int)f2bf(b.y) << 16);
  pk.w = (unsigned int)f2bf(b.z) | ((unsigned int)f2bf(b.w) << 16);
  *(uint4*)(A + (size_t)tid * 8) = pk;
}

// --- Kernel 2: W [d][K][N] fp32 -> Wt [d][N][K] bf16 (transpose + cast) ------
__global__ __launch_bounds__(256) void transpose_w_kernel(const float* __restrict__ W,
                                                          unsigned short* __restrict__ Wt) {
  __shared__ float tile[64][65];
  const int d  = blockIdx.z;
  const int k0 = blockIdx.x * 64;
  const int o0 = blockIdx.y * 64;
  const int t  = threadIdx.x;
  const float* src = W + (size_t)d * ((size_t)K_ * N_) + (size_t)k0 * N_ + o0;
  const int c4 = (t & 15) * 4;
  const int r  = t >> 4;
  #pragma unroll
  for (int j = 0; j < 64; j += 16) {
    float4 v = *(const float4*)(src + (size_t)(r + j) * N_ + c4);
    tile[r + j][c4 + 0] = v.x; tile[r + j][c4 + 1] = v.y;
    tile[r + j][c4 + 2] = v.z; tile[r + j][c4 + 3] = v.w;
  }
  __syncthreads();
  unsigned short* dst = Wt + (size_t)d * ((size_t)N_ * K_);
  const int kk = (t & 7) * 8;
  const int oo = t >> 3;
  #pragma unroll
  for (int p = 0; p < 64; p += 32) {
    const int o = oo + p;
    unsigned short tmp[8];
    #pragma unroll
    for (int i = 0; i < 8; i++) tmp[i] = f2bf(tile[kk + i][o]);
    *(uint4*)(dst + (size_t)(o0 + o) * K_ + k0 + kk) = *(uint4*)tmp;
  }
}

// --- Kernel 3: bf16 MFMA GEMM, deep-pipelined -------------------------------
// 256x256 tile, BK=32, 512 thr (8 waves, 2Mx4N; per-wave 128x64 output).
// 4-deep LDS ring buffer (4 x (16KB A + 16KB B) = 128 KiB): while computing
// K-tile t we ISSUE global_load_lds for tile t+3 into buffer (t+3)&3 — that
// buffer's reads (tile t-1) completed before the top-of-t barrier, so the
// async LDS write can never land on live data (issue-after-barrier => safe
// regardless of memory latency). Counted vmcnt(8) keeps the 2 younger tiles'
// loads in flight across barriers (T4); raw s_barrier avoids the compiler's
// vmcnt(0) drain that __syncthreads would force; setprio(1) wraps the 32-MFMA
// cluster (T5). One barrier + one waitcnt per K-tile = AITER-class density.
//
// LDS tile layout per buffer: [256 rows][4 chunks of 8 bf16], slot s of row r
// holds global k-chunk s^(r&3) (pre-swizzled global source, linear GLL dest —
// rule: swizzle both sides or neither). Frag ds_read_b128: lane(fr,qw) reads
// row base+fr, slot qw^(fr&3) -> uniform 8 lanes per bank-quad = conflict-free.
#define GLL16(gp, lp)                                                              \
  __builtin_amdgcn_global_load_lds(                                               \
      (const __attribute__((address_space(1))) void*)(gp),                        \
      (__attribute__((address_space(3))) void*)(lp), 16, 0, 0)

#define NT_ 64   // K_/32 K-tiles

__global__ __launch_bounds__(512, 2) void gemm_kernel(const unsigned short* __restrict__ A,
                                                      const unsigned short* __restrict__ Bt,
                                                      const float* __restrict__ bias,
                                                      float* __restrict__ C) {
  __shared__ __align__(16) unsigned short sA[4 * 8192];   // 64 KB: 4 ring slots x 256x32 bf16
  __shared__ __align__(16) unsigned short sB[4 * 8192];   // 64 KB
  const int tid  = threadIdx.x;
  const int w    = tid >> 6;        // wave 0..7
  const int lane = tid & 63;
  const int d    = blockIdx.z;

  // XCD-aware bijective swizzle: 256 blocks per d-slice, 256 % 8 == 0.
  const int lin     = blockIdx.y * 8 + blockIdx.x;          // 0..255
  const int tile_id = (lin & 7) * 32 + (lin >> 3);          // XCD k owns [32k, 32k+32)
  const int tileM   = (tile_id >> 3) * 256;                 // 32 M-tiles
  const int tileN   = (tile_id & 7) * 256;                  // 8  N-tiles

  // ---- staging lanes: 4 GLL16 per wave per K-tile (2 A + 2 B) ----
  // chunk q = w*128 + j*64 + lane: row = q>>2, slot = q&3; global chunk = slot^(row&3)
  const int lr = lane >> 2;                 // row within 16-row group
  const int ls = lane & 3;                  // LDS slot
  const int lc = ls ^ (lr & 3);             // pre-swizzled global k-chunk
  const unsigned short* gA0 = A + (size_t)(tileM + w * 32 + lr) * K_ + lc * 8;
  const unsigned short* gA1 = gA0 + (size_t)16 * K_;
  const unsigned short* Bd  = Bt + (size_t)d * ((size_t)N_ * K_);
  const unsigned short* gB0 = Bd + (size_t)(tileN + w * 32 + lr) * K_ + lc * 8;
  const unsigned short* gB1 = gB0 + (size_t)16 * K_;
  unsigned short* lA = sA + w * 1024;       // wave-uniform LDS bases (HW adds lane*16B)
  unsigned short* lB = sB + w * 1024;

  // ---- fragment lanes ----
  const int wr = w >> 2;                    // 0..1 (M half: 128 rows)
  const int wc = w & 3;                     // 0..3 (N quarter: 64 cols)
  const int fr = lane & 15;
  const int qw = lane >> 4;
  const int frag_off = fr * 32 + ((qw ^ (fr & 3)) * 8);   // elems; swizzled slot read
  const int aoff = wr * 4096 + frag_off;    // + mi*512
  const int boff = wc * 2048 + frag_off;    // + ni*512

  f32x4 acc[8][4];
  #pragma unroll
  for (int mi = 0; mi < 8; ++mi)
    #pragma unroll
    for (int ni = 0; ni < 4; ++ni)
      acc[mi][ni] = (f32x4){0.f, 0.f, 0.f, 0.f};

#define ISSUE_TILE(tt) do {                                                   \
    const int    bf_ = (tt) & 3;                                              \
    const size_t ko_ = (size_t)(tt) * 32;                                     \
    GLL16(gA0 + ko_, lA + bf_ * 8192);                                        \
    GLL16(gA1 + ko_, lA + bf_ * 8192 + 512);                                  \
    GLL16(gB0 + ko_, lB + bf_ * 8192);                                        \
    GLL16(gB1 + ko_, lB + bf_ * 8192 + 512);                                  \
  } while (0)

#define TILE_BODY(tt, WAITSTR, DOISSUE) do {                                  \
    asm volatile(WAITSTR ::: "memory");                                       \
    __builtin_amdgcn_s_barrier();                                             \
    __builtin_amdgcn_sched_barrier(0);                                        \
    if (DOISSUE) ISSUE_TILE((tt) + 3);                                        \
    const unsigned short* bA = sA + ((tt) & 3) * 8192 + aoff;                 \
    const unsigned short* bB = sB + ((tt) & 3) * 8192 + boff;                 \
    short8v af[8], bfv[4];                                                    \
    _Pragma("unroll")                                                         \
    for (int mi = 0; mi < 8; ++mi) af[mi]  = *(const short8v*)(bA + mi * 512);\
    _Pragma("unroll")                                                         \
    for (int ni = 0; ni < 4; ++ni) bfv[ni] = *(const short8v*)(bB + ni * 512);\
    __builtin_amdgcn_s_setprio(1);                                            \
    _Pragma("unroll")                                                         \
    for (int mi = 0; mi < 8; ++mi)                                            \
      _Pragma("unroll")                                                       \
      for (int ni = 0; ni < 4; ++ni)                                          \
        acc[mi][ni] = __builtin_amdgcn_mfma_f32_16x16x32_bf16(af[mi], bfv[ni],\
                                                              acc[mi][ni], 0, 0, 0); \
    __builtin_amdgcn_s_setprio(0);                                            \
  } while (0)

  // Prologue: fill 3 of 4 ring slots (12 loads/wave in flight).
  ISSUE_TILE(0); ISSUE_TILE(1); ISSUE_TILE(2);

  // Steady state: wait vmcnt(8) -> tile t landed, tiles t+1,t+2 in flight.
  for (int t = 0; t < NT_ - 2; ++t) {
    TILE_BODY(t, "s_waitcnt vmcnt(8)", t < NT_ - 3);
  }
  TILE_BODY(NT_ - 2, "s_waitcnt vmcnt(4)", false);
  TILE_BODY(NT_ - 1, "s_waitcnt vmcnt(0)", false);

#undef TILE_BODY
#undef ISSUE_TILE

  // Epilogue: C/D layout col=lane&15, row=(lane>>4)*4+reg [m89/m91-verified]
  float* Cd       = C + (size_t)d * ((size_t)M_ * N_);
  const float* bd = bias + d * N_;
  #pragma unroll
  for (int ni = 0; ni < 4; ++ni) {
    const int col  = tileN + wc * 64 + ni * 16 + fr;
    const float bv = bd[col];
    #pragma unroll
    for (int mi = 0; mi < 8; ++mi) {
      const int row0 = tileM + wr * 128 + mi * 16 + qw * 4;
      #pragma unroll
      for (int r = 0; r < 4; ++r)
        Cd[(size_t)(row0 + r) * N_ + col] = acc[mi][ni][r] + bv;
    }
  }
}

// --- Fallback: naive fp32 (only if d_ws is too small) ------------------------
__global__ void naive_kernel(const float* __restrict__ x, const float* __restrict__ W,
                             const float* __restrict__ bias, float* __restrict__ y) {
  long idx = (long)blockIdx.x * blockDim.x + threadIdx.x;
  if (idx >= (long)D_ * M_ * N_) return;
  int  n = (int)(idx % N_);
  long t = idx / N_;
  int  m = (int)(t % M_);
  int  d = (int)(t / M_);
  float acc = bias[d * N_ + n];
  const float* wd = W + (size_t)d * ((size_t)K_ * N_);
  for (int i = 0; i < D_; i++) {
    const float* xr = x + (size_t)i * ((size_t)M_ * DIN) + (size_t)m * DIN;
    const float* wr = wd + (size_t)i * ((size_t)DIN * N_) + n;
    #pragma unroll 4
    for (int k = 0; k < DIN; k++) acc += xr[k] * wr[(size_t)k * N_];
  }
  y[idx] = acc;
}

extern "C" void kernel_launch(void* const* d_in, const int* in_sizes, int n_in,
                              void* d_out, int out_size, void* d_ws, size_t ws_size,
                              hipStream_t stream) {
  const float* x    = (const float*)d_in[0];   // [4][2][4096][512] fp32
  const float* W    = (const float*)d_in[1];   // [4][4][512][2048] fp32
  const float* bias = (const float*)d_in[2];   // [4][2048] fp32
  float* out        = (float*)d_out;           // [4][2][4096][2048] fp32

  const size_t a_elems  = (size_t)M_ * K_;
  const size_t wt_elems = (size_t)D_ * N_ * K_;
  const size_t need     = (a_elems + wt_elems) * sizeof(unsigned short);

  if (ws_size >= need) {
    unsigned short* Abf = (unsigned short*)d_ws;
    unsigned short* Wt  = Abf + a_elems;

    convert_x_kernel<<<(M_ * K_ / 8) / 256, 256, 0, stream>>>(x, Abf);

    dim3 tgrid(K_ / 64, N_ / 64, D_);   // (32, 32, 4)
    transpose_w_kernel<<<tgrid, 256, 0, stream>>>(W, Wt);

    dim3 ggrid(N_ / 256, M_ / 256, D_); // (8, 32, 4) = 1024 blocks, 512 thr
    gemm_kernel<<<ggrid, 512, 0, stream>>>(Abf, Wt, bias, out);
  } else {
    long total = (long)D_ * M_ * N_;
    naive_kernel<<<(unsigned int)((total + 255) / 256), 256, 0, stream>>>(x, W, bias, out);
  }
}

// Round 4
// 588.435 us; speedup vs baseline: 1.1365x; 1.1365x over previous
//
#include <hip/hip_runtime.h>
#include <hip/hip_bf16.h>

// Problem constants (fixed by reference): D=4, B=2, S=4096, DIN_S=512, DOUT_S=2048
#define D_   4
#define M_   8192      // B*S
#define K_   2048      // D*DIN_S
#define N_   2048      // DOUT_S
#define DIN  512

typedef __attribute__((ext_vector_type(8))) short  short8v;   // 8 bf16 = 4 VGPRs (MFMA A/B frag)
typedef __attribute__((ext_vector_type(4))) float  f32x4;     // MFMA C/D frag

// fp32 -> bf16, round-to-nearest-even
__device__ __forceinline__ unsigned short f2bf(float f) {
  union { float f; unsigned int u; } v; v.f = f;
  unsigned int u = v.u;
  return (unsigned short)((u + 0x7fffu + ((u >> 16) & 1u)) >> 16);
}

// --- Kernel 1: x [i][m][k] fp32 -> A [m][i*512+k] bf16 (row-major M x K) -----
__global__ __launch_bounds__(256) void convert_x_kernel(const float* __restrict__ x,
                                                        unsigned short* __restrict__ A) {
  unsigned int tid = blockIdx.x * 256u + threadIdx.x;   // [0, M_*K_/8)
  unsigned int kg  = tid & 63u;
  unsigned int i   = (tid >> 6) & 3u;
  unsigned int m   = tid >> 8;
  const float4* src = (const float4*)(x + (size_t)i * ((size_t)M_ * DIN)
                                        + (size_t)m * DIN + (size_t)kg * 8);
  float4 a = src[0];
  float4 b = src[1];
  uint4 pk;
  pk.x = (unsigned int)f2bf(a.x) | ((unsigned int)f2bf(a.y) << 16);
  pk.y = (unsigned int)f2bf(a.z) | ((unsigned int)f2bf(a.w) << 16);
  pk.z = (unsigned int)f2bf(b.x) | ((unsigned int)f2bf(b.y) << 16);
  pk.w = (unsigned int)f2bf(b.z) | ((unsigned int)f2bf(b.w) << 16);
  *(uint4*)(A + (size_t)tid * 8) = pk;
}

// --- Kernel 2: W [d][K][N] fp32 -> Wt [d][N][K] bf16 (transpose + cast) ------
__global__ __launch_bounds__(256) void transpose_w_kernel(const float* __restrict__ W,
                                                          unsigned short* __restrict__ Wt) {
  __shared__ float tile[64][65];
  const int d  = blockIdx.z;
  const int k0 = blockIdx.x * 64;
  const int o0 = blockIdx.y * 64;
  const int t  = threadIdx.x;
  const float* src = W + (size_t)d * ((size_t)K_ * N_) + (size_t)k0 * N_ + o0;
  const int c4 = (t & 15) * 4;
  const int r  = t >> 4;
  #pragma unroll
  for (int j = 0; j < 64; j += 16) {
    float4 v = *(const float4*)(src + (size_t)(r + j) * N_ + c4);
    tile[r + j][c4 + 0] = v.x; tile[r + j][c4 + 1] = v.y;
    tile[r + j][c4 + 2] = v.z; tile[r + j][c4 + 3] = v.w;
  }
  __syncthreads();
  unsigned short* dst = Wt + (size_t)d * ((size_t)N_ * K_);
  const int kk = (t & 7) * 8;
  const int oo = t >> 3;
  #pragma unroll
  for (int p = 0; p < 64; p += 32) {
    const int o = oo + p;
    unsigned short tmp[8];
    #pragma unroll
    for (int i = 0; i < 8; i++) tmp[i] = f2bf(tile[kk + i][o]);
    *(uint4*)(dst + (size_t)(o0 + o) * K_ + k0 + kk) = *(uint4*)tmp;
  }
}

// --- Kernel 3: bf16 MFMA GEMM, deep-pipelined -------------------------------
// 256x256 tile, BK=32, 512 thr (8 waves, 2Mx4N; per-wave 128x64 output).
// Ring-4 LDS with INTERLEAVED A|B lines: line r (128 B) = [A-row r, 32 bf16 |
// B-row r, 32 bf16] = 8 chunks of 16 B. This restores the round-0-proven
// conflict-free geometry (128 B lines, 8-slot XOR): chunk c of line r is
// stored at slot c ^ (r&7). Staging keeps LDS dest LINEAR (global_load_lds
// requirement); the permutation is applied on the per-lane GLOBAL source:
// lane (slot=lane&7, lrow=lane>>3) fetches global chunk c = slot ^ lrow,
// which statically selects A (c<4) or B (c>=4). Fragment ds_read_b128 applies
// the same XOR on the read side -> 64 lanes cover 64 distinct 16 B slots
// spanning all 32 banks (round 0 measured SQ_LDS_BANK_CONFLICT == 0).
//
// Schedule (round-1-verified, kept): 4-deep ring; while computing tile t,
// issue tile t+3's 4 GLL (buffer (t+3)&3 was last read at t-1, whose reads
// completed before the top-of-t barrier -> overwrite is race-free). Counted
// s_waitcnt vmcnt(8) at top of tile (t's loads landed, t+1/t+2 stay in
// flight = T4, never drain to 0 in steady state); raw s_barrier (no
// compiler vmcnt(0) drain); setprio(1) around the 32-MFMA cluster (T5).
// Prefetch lead = 3 tile-times (~900+ cy) >= HBM-miss latency.
#define GLL16(gp, lp)                                                              \
  __builtin_amdgcn_global_load_lds(                                               \
      (const __attribute__((address_space(1))) void*)(gp),                        \
      (__attribute__((address_space(3))) void*)(lp), 16, 0, 0)

#define NT_ 64   // K_/32 K-tiles

__global__ __launch_bounds__(512, 2) void gemm_kernel(const unsigned short* __restrict__ A,
                                                      const unsigned short* __restrict__ Bt,
                                                      const float* __restrict__ bias,
                                                      float* __restrict__ C) {
  // 4 ring slots x 256 lines x 64 elems (A|B interleaved) = 128 KiB
  __shared__ __align__(16) unsigned short sT[4 * 16384];
  const int tid  = threadIdx.x;
  const int w    = tid >> 6;        // wave 0..7
  const int lane = tid & 63;
  const int d    = blockIdx.z;

  // XCD-aware bijective swizzle: 256 blocks per d-slice, 256 % 8 == 0.
  // Proven good in round 1: FETCH_SIZE 557 -> 197 MB.
  const int lin     = blockIdx.y * 8 + blockIdx.x;          // 0..255
  const int tile_id = (lin & 7) * 32 + (lin >> 3);          // XCD k owns [32k, 32k+32)
  const int tileM   = (tile_id >> 3) * 256;                 // 32 M-tiles
  const int tileN   = (tile_id & 7) * 256;                  // 8  N-tiles

  const unsigned short* Bd = Bt + (size_t)d * ((size_t)N_ * K_);

  // ---- staging lanes: 4 GLL16 per wave per K-tile ----
  // chunk q = w*256 + j*64 + lane: line = q>>3, slot = q&7; global chunk =
  // slot ^ (line&7) = (lane&7) ^ (lane>>3)  (static per lane).
  const int lrow = lane >> 3;               // 0..7 (line within 8-line group)
  const int lc   = (lane & 7) ^ lrow;       // global chunk 0..7: 0-3 = A, 4-7 = B
  const int crow = w * 32 + lrow;           // + j*8 per GLL round
  const unsigned short* gS =
      (lc < 4) ? (A  + (size_t)(tileM + crow) * K_ + lc * 8)
               : (Bd + (size_t)(tileN + crow) * K_ + (lc - 4) * 8);
  unsigned short* lW = sT + w * 2048;       // wave-uniform LDS base (+ ring, + j*512)

  // ---- fragment lanes ----
  const int wr = w >> 2;                    // 0..1 (M half: 128 rows)
  const int wc = w & 3;                     // 0..3 (N quarter: 64 cols)
  const int fr = lane & 15;
  const int qw = lane >> 4;
  const int xs = (qw ^ (fr & 7)) * 8;       // swizzled A-slot offset (elems)
  const int aoff = (wr * 128 + fr) * 64 + xs;          // + mi*1024
  const int boff = (wc *  64 + fr) * 64 + (xs ^ 32);   // + ni*1024 (B slots = A^4)

  f32x4 acc[8][4];
  #pragma unroll
  for (int mi = 0; mi < 8; ++mi)
    #pragma unroll
    for (int ni = 0; ni < 4; ++ni)
      acc[mi][ni] = (f32x4){0.f, 0.f, 0.f, 0.f};

#define ISSUE_TILE(tt) do {                                                   \
    unsigned short* lb_ = lW + ((tt) & 3) * 16384;                            \
    const size_t    ko_ = (size_t)(tt) * 32;                                  \
    GLL16(gS + ko_,                 lb_);                                     \
    GLL16(gS + ko_ + (size_t) 8*K_, lb_ +  512);                              \
    GLL16(gS + ko_ + (size_t)16*K_, lb_ + 1024);                              \
    GLL16(gS + ko_ + (size_t)24*K_, lb_ + 1536);                              \
  } while (0)

#define TILE_BODY(tt, WAITSTR, DOISSUE) do {                                  \
    asm volatile(WAITSTR ::: "memory");                                       \
    __builtin_amdgcn_s_barrier();                                             \
    __builtin_amdgcn_sched_barrier(0);                                        \
    if (DOISSUE) ISSUE_TILE((tt) + 3);                                        \
    const unsigned short* bT = sT + ((tt) & 3) * 16384;                       \
    short8v af[8], bfv[4];                                                    \
    _Pragma("unroll")                                                         \
    for (int mi = 0; mi < 8; ++mi) af[mi]  = *(const short8v*)(bT + aoff + mi * 1024); \
    _Pragma("unroll")                                                         \
    for (int ni = 0; ni < 4; ++ni) bfv[ni] = *(const short8v*)(bT + boff + ni * 1024); \
    __builtin_amdgcn_s_setprio(1);                                            \
    _Pragma("unroll")                                                         \
    for (int mi = 0; mi < 8; ++mi)                                            \
      _Pragma("unroll")                                                       \
      for (int ni = 0; ni < 4; ++ni)                                          \
        acc[mi][ni] = __builtin_amdgcn_mfma_f32_16x16x32_bf16(af[mi], bfv[ni],\
                                                              acc[mi][ni], 0, 0, 0); \
    __builtin_amdgcn_s_setprio(0);                                            \
  } while (0)

  // Prologue: fill 3 of 4 ring slots (12 loads/wave in flight).
  ISSUE_TILE(0); ISSUE_TILE(1); ISSUE_TILE(2);

  // Steady state: vmcnt(8) -> tile t landed; t+1, t+2 stay in flight.
  for (int t = 0; t < NT_ - 2; ++t) {
    TILE_BODY(t, "s_waitcnt vmcnt(8)", t < NT_ - 3);
  }
  TILE_BODY(NT_ - 2, "s_waitcnt vmcnt(4)", false);
  TILE_BODY(NT_ - 1, "s_waitcnt vmcnt(0)", false);

#undef TILE_BODY
#undef ISSUE_TILE

  // Epilogue: C/D layout col=lane&15, row=(lane>>4)*4+reg [m89/m91-verified]
  float* Cd       = C + (size_t)d * ((size_t)M_ * N_);
  const float* bd = bias + d * N_;
  #pragma unroll
  for (int ni = 0; ni < 4; ++ni) {
    const int col  = tileN + wc * 64 + ni * 16 + fr;
    const float bv = bd[col];
    #pragma unroll
    for (int mi = 0; mi < 8; ++mi) {
      const int row0 = tileM + wr * 128 + mi * 16 + qw * 4;
      #pragma unroll
      for (int r = 0; r < 4; ++r)
        Cd[(size_t)(row0 + r) * N_ + col] = acc[mi][ni][r] + bv;
    }
  }
}

// --- Fallback: naive fp32 (only if d_ws is too small) ------------------------
__global__ void naive_kernel(const float* __restrict__ x, const float* __restrict__ W,
                             const float* __restrict__ bias, float* __restrict__ y) {
  long idx = (long)blockIdx.x * blockDim.x + threadIdx.x;
  if (idx >= (long)D_ * M_ * N_) return;
  int  n = (int)(idx % N_);
  long t = idx / N_;
  int  m = (int)(t % M_);
  int  d = (int)(t / M_);
  float acc = bias[d * N_ + n];
  const float* wd = W + (size_t)d * ((size_t)K_ * N_);
  for (int i = 0; i < D_; i++) {
    const float* xr = x + (size_t)i * ((size_t)M_ * DIN) + (size_t)m * DIN;
    const float* wr = wd + (size_t)i * ((size_t)DIN * N_) + n;
    #pragma unroll 4
    for (int k = 0; k < DIN; k++) acc += xr[k] * wr[(size_t)k * N_];
  }
  y[idx] = acc;
}

extern "C" void kernel_launch(void* const* d_in, const int* in_sizes, int n_in,
                              void* d_out, int out_size, void* d_ws, size_t ws_size,
                              hipStream_t stream) {
  const float* x    = (const float*)d_in[0];   // [4][2][4096][512] fp32
  const float* W    = (const float*)d_in[1];   // [4][4][512][2048] fp32
  const float* bias = (const float*)d_in[2];   // [4][2048] fp32
  float* out        = (float*)d_out;           // [4][2][4096][2048] fp32

  const size_t a_elems  = (size_t)M_ * K_;
  const size_t wt_elems = (size_t)D_ * N_ * K_;
  const size_t need     = (a_elems + wt_elems) * sizeof(unsigned short);

  if (ws_size >= need) {
    unsigned short* Abf = (unsigned short*)d_ws;
    unsigned short* Wt  = Abf + a_elems;

    convert_x_kernel<<<(M_ * K_ / 8) / 256, 256, 0, stream>>>(x, Abf);

    dim3 tgrid(K_ / 64, N_ / 64, D_);   // (32, 32, 4)
    transpose_w_kernel<<<tgrid, 256, 0, stream>>>(W, Wt);

    dim3 ggrid(N_ / 256, M_ / 256, D_); // (8, 32, 4) = 1024 blocks, 512 thr
    gemm_kernel<<<ggrid, 512, 0, stream>>>(Abf, Wt, bias, out);
  } else {
    long total = (long)D_ * M_ * N_;
    naive_kernel<<<(unsigned int)((total + 255) / 256), 256, 0, stream>>>(x, W, bias, out);
  }
}

// Round 5
// 577.629 us; speedup vs baseline: 1.1578x; 1.0187x over previous
//
#include <hip/hip_runtime.h>
#include <hip/hip_bf16.h>

// Problem constants (fixed by reference): D=4, B=2, S=4096, DIN_S=512, DOUT_S=2048
#define D_   4
#define M_   8192      // B*S
#define K_   2048      // D*DIN_S
#define N_   2048      // DOUT_S
#define DIN  512

typedef __attribute__((ext_vector_type(8))) short  short8v;   // 8 bf16 = 4 VGPRs (MFMA A/B frag)
typedef __attribute__((ext_vector_type(4))) float  f32x4;     // MFMA C/D frag

// fp32 -> bf16, round-to-nearest-even
__device__ __forceinline__ unsigned short f2bf(float f) {
  union { float f; unsigned int u; } v; v.f = f;
  unsigned int u = v.u;
  return (unsigned short)((u + 0x7fffu + ((u >> 16) & 1u)) >> 16);
}

// --- Kernel 1: x [i][m][k] fp32 -> A [m][i*512+k] bf16 (row-major M x K) -----
__global__ __launch_bounds__(256) void convert_x_kernel(const float* __restrict__ x,
                                                        unsigned short* __restrict__ A) {
  unsigned int tid = blockIdx.x * 256u + threadIdx.x;   // [0, M_*K_/8)
  unsigned int kg  = tid & 63u;
  unsigned int i   = (tid >> 6) & 3u;
  unsigned int m   = tid >> 8;
  const float4* src = (const float4*)(x + (size_t)i * ((size_t)M_ * DIN)
                                        + (size_t)m * DIN + (size_t)kg * 8);
  float4 a = src[0];
  float4 b = src[1];
  uint4 pk;
  pk.x = (unsigned int)f2bf(a.x) | ((unsigned int)f2bf(a.y) << 16);
  pk.y = (unsigned int)f2bf(a.z) | ((unsigned int)f2bf(a.w) << 16);
  pk.z = (unsigned int)f2bf(b.x) | ((unsigned int)f2bf(b.y) << 16);
  pk.w = (unsigned int)f2bf(b.z) | ((unsigned int)f2bf(b.w) << 16);
  *(uint4*)(A + (size_t)tid * 8) = pk;
}

// --- Kernel 2: W [d][K][N] fp32 -> Wt [d][N][K] bf16 (transpose + cast) ------
__global__ __launch_bounds__(256) void transpose_w_kernel(const float* __restrict__ W,
                                                          unsigned short* __restrict__ Wt) {
  __shared__ float tile[64][65];
  const int d  = blockIdx.z;
  const int k0 = blockIdx.x * 64;
  const int o0 = blockIdx.y * 64;
  const int t  = threadIdx.x;
  const float* src = W + (size_t)d * ((size_t)K_ * N_) + (size_t)k0 * N_ + o0;
  const int c4 = (t & 15) * 4;
  const int r  = t >> 4;
  #pragma unroll
  for (int j = 0; j < 64; j += 16) {
    float4 v = *(const float4*)(src + (size_t)(r + j) * N_ + c4);
    tile[r + j][c4 + 0] = v.x; tile[r + j][c4 + 1] = v.y;
    tile[r + j][c4 + 2] = v.z; tile[r + j][c4 + 3] = v.w;
  }
  __syncthreads();
  unsigned short* dst = Wt + (size_t)d * ((size_t)N_ * K_);
  const int kk = (t & 7) * 8;
  const int oo = t >> 3;
  #pragma unroll
  for (int p = 0; p < 64; p += 32) {
    const int o = oo + p;
    unsigned short tmp[8];
    #pragma unroll
    for (int i = 0; i < 8; i++) tmp[i] = f2bf(tile[kk + i][o]);
    *(uint4*)(dst + (size_t)(o0 + o) * K_ + k0 + kk) = *(uint4*)tmp;
  }
}

// --- Kernel 3: bf16 MFMA GEMM, 8-phase deep pipeline ------------------------
// 256x256 tile, BK=32, 512 thr (8 waves, 2Mx4N; per-wave 128x64 output).
// LDS: ring-4 of interleaved A|B lines (round-4-verified ZERO bank conflicts):
// line r (128 B) = [A-row r | B-row r], 8 chunks of 16 B, chunk c stored at
// slot c^(r&7); staging keeps LDS dest linear and applies the permutation on
// the per-lane GLOBAL source (lane's chunk = (lane&7)^(lane>>3), statically
// A or B); fragment ds_read_b128 applies the same XOR on the read side.
//
// NEW this round — T3 phase interleave (m201 granularity: 16 MFMA/phase,
// 2 barriers/phase, vmcnt once per K-tile):
//   P0: ds_read af[0-3]+bf[0-3] (8 b128) + 2 GLL(t+3) -> barrier ->
//       lgkmcnt(0) -> setprio(1) 16 MFMA setprio(0) -> barrier
//   P1: ds_read af[4-7] (4 b128; B stays in regs) + 2 GLL(t+3) -> barrier ->
//       lgkmcnt(0) -> setprio(1) 16 MFMA setprio(0) -> vmcnt(8) -> barrier
// Round 4's 1-phase structure measured MfmaUtil 46%: all 8 waves in lockstep
// burst 12 ds_reads then 32 MFMAs -> LDS and MFMA pipes serialize. The
// per-phase interleave is the documented regime gate (m196/m201: 62% util).
//
// Ring safety: GLL for tile t+3 overwrites slot (t-1)&3, whose last ds_read
// completed at tile t-1's P1 lgkmcnt(0); every wave passes that before the
// inter-tile barrier, and the GLL issues after it -> race-free. vmcnt(8) at
// tile end = own 4 loads of tile t+1 landed, t+2/t+3 (8) stay in flight
// (counted, never drained to 0 in steady state). Tail: vmcnt(4)/vmcnt(0).
#define GLL16(gp, lp)                                                              \
  __builtin_amdgcn_global_load_lds(                                               \
      (const __attribute__((address_space(1))) void*)(gp),                        \
      (__attribute__((address_space(3))) void*)(lp), 16, 0, 0)

#define NT_ 64   // K_/32 K-tiles

__global__ __launch_bounds__(512, 2) void gemm_kernel(const unsigned short* __restrict__ A,
                                                      const unsigned short* __restrict__ Bt,
                                                      const float* __restrict__ bias,
                                                      float* __restrict__ C) {
  // 4 ring slots x 256 lines x 64 elems (A|B interleaved) = 128 KiB
  __shared__ __align__(16) unsigned short sT[4 * 16384];
  const int tid  = threadIdx.x;
  const int w    = tid >> 6;        // wave 0..7
  const int lane = tid & 63;
  const int d    = blockIdx.z;

  // XCD-aware bijective swizzle: 256 blocks per d-slice, 256 % 8 == 0.
  // Proven: FETCH_SIZE 557 -> 197 MB.
  const int lin     = blockIdx.y * 8 + blockIdx.x;          // 0..255
  const int tile_id = (lin & 7) * 32 + (lin >> 3);          // XCD k owns [32k, 32k+32)
  const int tileM   = (tile_id >> 3) * 256;                 // 32 M-tiles
  const int tileN   = (tile_id & 7) * 256;                  // 8  N-tiles

  const unsigned short* Bd = Bt + (size_t)d * ((size_t)N_ * K_);

  // ---- staging lanes: 4 GLL16 per wave per K-tile (2 in P0, 2 in P1) ----
  const int lrow = lane >> 3;               // 0..7 (line within 8-line group)
  const int lc   = (lane & 7) ^ lrow;       // global chunk 0..7: 0-3 = A, 4-7 = B
  const int crow = w * 32 + lrow;           // + j*8 per GLL round
  const unsigned short* gS =
      (lc < 4) ? (A  + (size_t)(tileM + crow) * K_ + lc * 8)
               : (Bd + (size_t)(tileN + crow) * K_ + (lc - 4) * 8);
  unsigned short* lW = sT + w * 2048;       // wave-uniform LDS base (+ ring, + j*512)

  // ---- fragment lanes ----
  const int wr = w >> 2;                    // 0..1 (M half: 128 rows)
  const int wc = w & 3;                     // 0..3 (N quarter: 64 cols)
  const int fr = lane & 15;
  const int qw = lane >> 4;
  const int xs = (qw ^ (fr & 7)) * 8;       // swizzled A-slot offset (elems)
  const int aoff = (wr * 128 + fr) * 64 + xs;          // + mi*1024
  const int boff = (wc *  64 + fr) * 64 + (xs ^ 32);   // + ni*1024 (B slots = A^4)

  f32x4 acc[8][4];
  #pragma unroll
  for (int mi = 0; mi < 8; ++mi)
    #pragma unroll
    for (int ni = 0; ni < 4; ++ni)
      acc[mi][ni] = (f32x4){0.f, 0.f, 0.f, 0.f};

#define ISSUE_TILE(tt) do {                                                   \
    unsigned short* lb_ = lW + ((tt) & 3) * 16384;                            \
    const size_t    ko_ = (size_t)(tt) * 32;                                  \
    GLL16(gS + ko_,                 lb_);                                     \
    GLL16(gS + ko_ + (size_t) 8*K_, lb_ +  512);                              \
    GLL16(gS + ko_ + (size_t)16*K_, lb_ + 1024);                              \
    GLL16(gS + ko_ + (size_t)24*K_, lb_ + 1536);                              \
  } while (0)

#define ISSUE_HALF(tt, jj) do {                                               \
    unsigned short* lb_ = lW + ((tt) & 3) * 16384;                            \
    const size_t    ko_ = (size_t)(tt) * 32;                                  \
    GLL16(gS + ko_ + (size_t)(jj)     * 8 * K_, lb_ + (jj) * 512);            \
    GLL16(gS + ko_ + (size_t)((jj)+1) * 8 * K_, lb_ + ((jj)+1) * 512);        \
  } while (0)

#define TILE_BODY(tt, ENDWAIT, DOISSUE) do {                                  \
    const unsigned short* bT = sT + ((tt) & 3) * 16384;                       \
    short8v afv[4], bfv[4];                                                   \
    /* ---------- phase 0: af rows 0-3, all bf ---------- */                  \
    _Pragma("unroll")                                                         \
    for (int mi = 0; mi < 4; ++mi) afv[mi] = *(const short8v*)(bT + aoff + mi * 1024); \
    _Pragma("unroll")                                                         \
    for (int ni = 0; ni < 4; ++ni) bfv[ni] = *(const short8v*)(bT + boff + ni * 1024); \
    if (DOISSUE) ISSUE_HALF((tt) + 3, 0);                                     \
    __builtin_amdgcn_s_barrier();                                             \
    asm volatile("s_waitcnt lgkmcnt(0)" ::: "memory");                        \
    __builtin_amdgcn_sched_barrier(0);                                        \
    __builtin_amdgcn_s_setprio(1);                                            \
    _Pragma("unroll")                                                         \
    for (int mi = 0; mi < 4; ++mi)                                            \
      _Pragma("unroll")                                                       \
      for (int ni = 0; ni < 4; ++ni)                                          \
        acc[mi][ni] = __builtin_amdgcn_mfma_f32_16x16x32_bf16(afv[mi], bfv[ni],\
                                                              acc[mi][ni], 0, 0, 0); \
    __builtin_amdgcn_s_setprio(0);                                            \
    __builtin_amdgcn_sched_barrier(0);                                        \
    __builtin_amdgcn_s_barrier();                                             \
    /* ---------- phase 1: af rows 4-7, reuse bf ---------- */                \
    _Pragma("unroll")                                                         \
    for (int mi = 0; mi < 4; ++mi) afv[mi] = *(const short8v*)(bT + aoff + (mi + 4) * 1024); \
    if (DOISSUE) ISSUE_HALF((tt) + 3, 2);                                     \
    __builtin_amdgcn_s_barrier();                                             \
    asm volatile("s_waitcnt lgkmcnt(0)" ::: "memory");                        \
    __builtin_amdgcn_sched_barrier(0);                                        \
    __builtin_amdgcn_s_setprio(1);                                            \
    _Pragma("unroll")                                                         \
    for (int mi = 0; mi < 4; ++mi)                                            \
      _Pragma("unroll")                                                       \
      for (int ni = 0; ni < 4; ++ni)                                          \
        acc[mi + 4][ni] = __builtin_amdgcn_mfma_f32_16x16x32_bf16(afv[mi], bfv[ni],\
                                                                  acc[mi + 4][ni], 0, 0, 0); \
    __builtin_amdgcn_s_setprio(0);                                            \
    __builtin_amdgcn_sched_barrier(0);                                        \
    asm volatile(ENDWAIT ::: "memory");                                       \
    __builtin_amdgcn_s_barrier();                                             \
  } while (0)

  // Prologue: fill 3 of 4 ring slots; drain to tile-0-ready (8 in flight).
  ISSUE_TILE(0); ISSUE_TILE(1); ISSUE_TILE(2);
  asm volatile("s_waitcnt vmcnt(8)" ::: "memory");
  __builtin_amdgcn_s_barrier();

  // Steady state: end-of-tile vmcnt(8) -> tile t+1 landed; t+2, t+3 in flight.
  for (int t = 0; t < NT_ - 3; ++t) {
    TILE_BODY(t, "s_waitcnt vmcnt(8)", true);
  }
  TILE_BODY(NT_ - 3, "s_waitcnt vmcnt(4)", false);
  TILE_BODY(NT_ - 2, "s_waitcnt vmcnt(0)", false);
  TILE_BODY(NT_ - 1, "s_nop 0", false);

#undef TILE_BODY
#undef ISSUE_HALF
#undef ISSUE_TILE

  // Epilogue: C/D layout col=lane&15, row=(lane>>4)*4+reg [m89/m91-verified]
  float* Cd       = C + (size_t)d * ((size_t)M_ * N_);
  const float* bd = bias + d * N_;
  #pragma unroll
  for (int ni = 0; ni < 4; ++ni) {
    const int col  = tileN + wc * 64 + ni * 16 + fr;
    const float bv = bd[col];
    #pragma unroll
    for (int mi = 0; mi < 8; ++mi) {
      const int row0 = tileM + wr * 128 + mi * 16 + qw * 4;
      #pragma unroll
      for (int r = 0; r < 4; ++r)
        Cd[(size_t)(row0 + r) * N_ + col] = acc[mi][ni][r] + bv;
    }
  }
}

// --- Fallback: naive fp32 (only if d_ws is too small) ------------------------
__global__ void naive_kernel(const float* __restrict__ x, const float* __restrict__ W,
                             const float* __restrict__ bias, float* __restrict__ y) {
  long idx = (long)blockIdx.x * blockDim.x + threadIdx.x;
  if (idx >= (long)D_ * M_ * N_) return;
  int  n = (int)(idx % N_);
  long t = idx / N_;
  int  m = (int)(t % M_);
  int  d = (int)(t / M_);
  float acc = bias[d * N_ + n];
  const float* wd = W + (size_t)d * ((size_t)K_ * N_);
  for (int i = 0; i < D_; i++) {
    const float* xr = x + (size_t)i * ((size_t)M_ * DIN) + (size_t)m * DIN;
    const float* wr = wd + (size_t)i * ((size_t)DIN * N_) + n;
    #pragma unroll 4
    for (int k = 0; k < DIN; k++) acc += xr[k] * wr[(size_t)k * N_];
  }
  y[idx] = acc;
}

extern "C" void kernel_launch(void* const* d_in, const int* in_sizes, int n_in,
                              void* d_out, int out_size, void* d_ws, size_t ws_size,
                              hipStream_t stream) {
  const float* x    = (const float*)d_in[0];   // [4][2][4096][512] fp32
  const float* W    = (const float*)d_in[1];   // [4][4][512][2048] fp32
  const float* bias = (const float*)d_in[2];   // [4][2048] fp32
  float* out        = (float*)d_out;           // [4][2][4096][2048] fp32

  const size_t a_elems  = (size_t)M_ * K_;
  const size_t wt_elems = (size_t)D_ * N_ * K_;
  const size_t need     = (a_elems + wt_elems) * sizeof(unsigned short);

  if (ws_size >= need) {
    unsigned short* Abf = (unsigned short*)d_ws;
    unsigned short* Wt  = Abf + a_elems;

    convert_x_kernel<<<(M_ * K_ / 8) / 256, 256, 0, stream>>>(x, Abf);

    dim3 tgrid(K_ / 64, N_ / 64, D_);   // (32, 32, 4)
    transpose_w_kernel<<<tgrid, 256, 0, stream>>>(W, Wt);

    dim3 ggrid(N_ / 256, M_ / 256, D_); // (8, 32, 4) = 1024 blocks, 512 thr
    gemm_kernel<<<ggrid, 512, 0, stream>>>(Abf, Wt, bias, out);
  } else {
    long total = (long)D_ * M_ * N_;
    naive_kernel<<<(unsigned int)((total + 255) / 256), 256, 0, stream>>>(x, W, bias, out);
  }
}